// Round 5
// baseline (536.862 us; speedup 1.0000x reference)
//
#include <hip/hip_runtime.h>
#include <math.h>

#define N_NODES_C 50000
#define E_C       800000
#define ATT_IN_C  176
#define ATT_HID_C 144
#define SCAN_B    98      // ceil(50000 / 512)
#define UPD_TILES 3125    // 50000 / 16 exact
#define SC_BLOCKS 512     // 2048 waves = 2 waves/SIMD

typedef __attribute__((ext_vector_type(8))) __bf16 bf16x8;
typedef __attribute__((ext_vector_type(4))) float f32x4;

// workspace layout (bytes, 1KB aligned)
#define O_RAW   0L          // float[E]
#define O_DEG   3201024L    // int[N]
#define O_OFF   3402752L    // int[N+1]
#define O_CUR   3603456L    // int[N]
#define O_CSR   3804160L    // int2[E] (src,dst) per CSR slot
#define O_EFP   10206208L   // bf16[E*16] permuted edge features
#define O_XB    35807232L   // bf16[N*64]
#define O_XSB   42208256L   // bf16[N*16]
#define O_W1B   43809280L   // bf16[144*176]
#define O_UW1B  43860992L   // bf16[128*128]
#define O_UW2B  43894784L   // bf16[64*128]
#define O_AGGB  43912192L   // bf16[N*64]  (psum/boff borrow head; dead by k_agg)
#define O_PSUM  O_AGGB
#define O_BOFF  (O_AGGB + 512L)

__device__ __forceinline__ bf16x8 bzero8() {
    bf16x8 z;
#pragma unroll
    for (int i = 0; i < 8; ++i) z[i] = (__bf16)0.0f;
    return z;
}

__global__ __launch_bounds__(256) void k_deg(const int* __restrict__ ei, int* __restrict__ deg) {
    int e = blockIdx.x * blockDim.x + threadIdx.x;
    if (e < E_C) atomicAdd(&deg[ei[E_C + e]], 1);
}

// ---- 3-phase parallel scan of deg -> offsets/cursor
__global__ __launch_bounds__(256) void k_scan1(const int* __restrict__ deg,
                                               int* __restrict__ psum) {
    __shared__ int red[256];
    int b = blockIdx.x, t = threadIdx.x;
    int i = b * 512 + t * 2;
    int s = 0;
    if (i < N_NODES_C) s += deg[i];
    if (i + 1 < N_NODES_C) s += deg[i + 1];
    red[t] = s;
    __syncthreads();
#pragma unroll
    for (int off = 128; off > 0; off >>= 1) {
        if (t < off) red[t] += red[t + off];
        __syncthreads();
    }
    if (t == 0) psum[b] = red[0];
}

__global__ __launch_bounds__(128) void k_scan2(const int* __restrict__ psum,
                                               int* __restrict__ boff,
                                               int* __restrict__ offsets) {
    __shared__ int sc[128];
    int t = threadIdx.x;
    int v = (t < SCAN_B) ? psum[t] : 0;
    sc[t] = v;
    __syncthreads();
#pragma unroll
    for (int off = 1; off < 128; off <<= 1) {
        int val = sc[t];
        int add = (t >= off) ? sc[t - off] : 0;
        __syncthreads();
        sc[t] = val + add;
        __syncthreads();
    }
    boff[t] = sc[t] - v;
    if (t == SCAN_B - 1) offsets[N_NODES_C] = sc[t];
}

__global__ __launch_bounds__(256) void k_scan3(const int* __restrict__ deg,
                                               const int* __restrict__ boff,
                                               int* __restrict__ offsets,
                                               int* __restrict__ cursor) {
    __shared__ int sc[256];
    int b = blockIdx.x, t = threadIdx.x;
    int i = b * 512 + t * 2;
    int d0 = (i < N_NODES_C) ? deg[i] : 0;
    int d1 = (i + 1 < N_NODES_C) ? deg[i + 1] : 0;
    int s = d0 + d1;
    sc[t] = s;
    __syncthreads();
#pragma unroll
    for (int off = 1; off < 256; off <<= 1) {
        int val = sc[t];
        int add = (t >= off) ? sc[t - off] : 0;
        __syncthreads();
        sc[t] = val + add;
        __syncthreads();
    }
    int excl = boff[b] + sc[t] - s;
    if (i < N_NODES_C)     { offsets[i]     = excl;      cursor[i]     = excl; }
    if (i + 1 < N_NODES_C) { offsets[i + 1] = excl + d0; cursor[i + 1] = excl + d0; }
}

// ---- CSR fill + ef permute/convert
__global__ __launch_bounds__(256) void k_fill(const int* __restrict__ ei,
                                              const float* __restrict__ ef,
                                              int* __restrict__ cursor,
                                              int2* __restrict__ csr,
                                              __bf16* __restrict__ efp) {
    int e = blockIdx.x * blockDim.x + threadIdx.x;
    if (e < E_C) {
        int src  = ei[e];
        int dst  = ei[E_C + e];
        int slot = atomicAdd(&cursor[dst], 1);
        csr[slot] = make_int2(src, dst);
        const float4* pe = (const float4*)(ef + (long)e * 16);
        float4 f0 = pe[0], f1 = pe[1], f2 = pe[2], f3 = pe[3];
        bf16x8 o0, o1;
        o0[0] = (__bf16)f0.x; o0[1] = (__bf16)f0.y; o0[2] = (__bf16)f0.z; o0[3] = (__bf16)f0.w;
        o0[4] = (__bf16)f1.x; o0[5] = (__bf16)f1.y; o0[6] = (__bf16)f1.z; o0[7] = (__bf16)f1.w;
        o1[0] = (__bf16)f2.x; o1[1] = (__bf16)f2.y; o1[2] = (__bf16)f2.z; o1[3] = (__bf16)f2.w;
        o1[4] = (__bf16)f3.x; o1[5] = (__bf16)f3.y; o1[6] = (__bf16)f3.z; o1[7] = (__bf16)f3.w;
        *(bf16x8*)(efp + (long)slot * 16)     = o0;
        *(bf16x8*)(efp + (long)slot * 16 + 8) = o1;
    }
}

// ---- fp32 -> bf16 conversion: x, xs, att_w1, upd_w1, upd_w2
__global__ __launch_bounds__(256) void k_cvt(
    const float* __restrict__ x, const float* __restrict__ xs,
    const float* __restrict__ w1, const float* __restrict__ uw1,
    const float* __restrict__ uw2,
    __bf16* __restrict__ xb, __bf16* __restrict__ xsb,
    __bf16* __restrict__ w1b, __bf16* __restrict__ uw1b,
    __bf16* __restrict__ uw2b)
{
    long g = (long)blockIdx.x * 256 + threadIdx.x;  // one group = 8 floats
    const long G_X = 400000, G_XS = 500000, G_W1 = 503168, G_UW1 = 505216, G_UW2 = 506240;
    if (g >= G_UW2) return;
    const float* src; __bf16* dst; long off;
    if (g < G_X)        { src = x;   dst = xb;   off = g * 8; }
    else if (g < G_XS)  { src = xs;  dst = xsb;  off = (g - G_X) * 8; }
    else if (g < G_W1)  { src = w1;  dst = w1b;  off = (g - G_XS) * 8; }
    else if (g < G_UW1) { src = uw1; dst = uw1b; off = (g - G_W1) * 8; }
    else                { src = uw2; dst = uw2b; off = (g - G_UW1) * 8; }
    float4 a = *(const float4*)(src + off);
    float4 b = *(const float4*)(src + off + 4);
    bf16x8 o;
    o[0] = (__bf16)a.x; o[1] = (__bf16)a.y; o[2] = (__bf16)a.z; o[3] = (__bf16)a.w;
    o[4] = (__bf16)b.x; o[5] = (__bf16)b.y; o[6] = (__bf16)b.z; o[7] = (__bf16)b.w;
    *(bf16x8*)(dst + off) = o;
}

// ---- A-fragment gather (CSR order: p = t*16 + mrow; efp contiguous)
__device__ __forceinline__ void load_afrags(
    int src, int dst, long t, int mrow, int quad,
    const __bf16* __restrict__ xb, const __bf16* __restrict__ xsb,
    const __bf16* __restrict__ efp,
    bf16x8 a[6])
{
    long p = t * 16 + mrow;
    const __bf16* px = xb + (long)src * 64 + quad * 8;
    const __bf16* pd = xb + (long)dst * 64 + quad * 8;
    a[0] = *(const bf16x8*)(px);
    a[1] = *(const bf16x8*)(px + 32);
    a[2] = *(const bf16x8*)(pd);
    a[3] = *(const bf16x8*)(pd + 32);
    if (quad < 2) {
        a[4] = *(const bf16x8*)(xsb + (long)src * 16 + quad * 8);
        a[5] = *(const bf16x8*)(efp + p * 16 + quad * 8);
    } else {
        a[4] = *(const bf16x8*)(xsb + (long)dst * 16 + (quad - 2) * 8);
        a[5] = bzero8();
    }
}

// ---- edge attention MLP via bf16 MFMA, CSR-ordered, 2 waves/SIMD
__global__ __launch_bounds__(256, 2) void k_scores_mfma(
    const __bf16* __restrict__ xb, const __bf16* __restrict__ xsb,
    const __bf16* __restrict__ efp, const __bf16* __restrict__ w1b,
    const int2* __restrict__ csr,
    const float* __restrict__ b1, const float* __restrict__ w2,
    const float* __restrict__ b2, float* __restrict__ raw)
{
    int tid  = threadIdx.x;
    int lane = tid & 63;
    int w    = blockIdx.x * 4 + (tid >> 6);   // global wave 0..2047
    const int NT = E_C / 16;
    const int TOT_W = SC_BLOCKS * 4;
    int per = (NT + TOT_W - 1) / TOT_W;       // 25
    long t0 = (long)w * per;
    long t1 = t0 + per; if (t1 > NT) t1 = NT;
    if (t0 >= t1) return;

    int mrow = lane & 15;
    int quad = lane >> 4;

    bf16x8 bfr[6][9];
#pragma unroll
    for (int ks = 0; ks < 6; ++ks) {
        int k0 = ks * 32 + quad * 8;
#pragma unroll
        for (int nt = 0; nt < 9; ++nt) {
            int n = nt * 16 + mrow;
            if (k0 + 8 <= ATT_IN_C)
                bfr[ks][nt] = *(const bf16x8*)(w1b + (long)n * ATT_IN_C + k0);
            else
                bfr[ks][nt] = bzero8();
        }
    }

    float b1v[9], w2v[9];
#pragma unroll
    for (int nt = 0; nt < 9; ++nt) {
        int n = nt * 16 + mrow;
        b1v[nt] = b1[n];
        w2v[nt] = w2[n];
    }
    float b2v = b2[0];

    bf16x8 acur[6], anext[6];
    int ns = 0, nd = 0;
    {
        int2 c0 = csr[t0 * 16 + mrow];
        load_afrags(c0.x, c0.y, t0, mrow, quad, xb, xsb, efp, acur);
        if (t0 + 1 < t1) {
            int2 c1 = csr[(t0 + 1) * 16 + mrow];
            load_afrags(c1.x, c1.y, t0 + 1, mrow, quad, xb, xsb, efp, anext);
        }
    }

    for (long t = t0; t < t1; ++t) {
        if (t + 2 < t1) {
            int2 c2 = csr[(t + 2) * 16 + mrow];
            ns = c2.x;
            nd = c2.y;
        }

        f32x4 acc[9];
#pragma unroll
        for (int nt = 0; nt < 9; ++nt) acc[nt] = (f32x4){0.f, 0.f, 0.f, 0.f};

#pragma unroll
        for (int ks = 0; ks < 6; ++ks) {
#pragma unroll
            for (int nt = 0; nt < 9; ++nt) {
                acc[nt] = __builtin_amdgcn_mfma_f32_16x16x32_bf16(
                    acur[ks], bfr[ks][nt], acc[nt], 0, 0, 0);
            }
        }

        float p0 = 0.f, p1 = 0.f, p2 = 0.f, p3 = 0.f;
#pragma unroll
        for (int nt = 0; nt < 9; ++nt) {
            p0 += w2v[nt] * fmaxf(acc[nt][0] + b1v[nt], 0.f);
            p1 += w2v[nt] * fmaxf(acc[nt][1] + b1v[nt], 0.f);
            p2 += w2v[nt] * fmaxf(acc[nt][2] + b1v[nt], 0.f);
            p3 += w2v[nt] * fmaxf(acc[nt][3] + b1v[nt], 0.f);
        }
#pragma unroll
        for (int off = 1; off < 16; off <<= 1) {
            p0 += __shfl_xor(p0, off, 64);
            p1 += __shfl_xor(p1, off, 64);
            p2 += __shfl_xor(p2, off, 64);
            p3 += __shfl_xor(p3, off, 64);
        }
        if (mrow < 4) {
            float v = (mrow == 0) ? p0 : (mrow == 1) ? p1 : (mrow == 2) ? p2 : p3;
            v += b2v;
            v = (v >= 0.f) ? v : 0.01f * v;
            raw[t * 16 + quad * 4 + mrow] = v;
        }

#pragma unroll
        for (int i = 0; i < 6; ++i) acur[i] = anext[i];
        if (t + 2 < t1)
            load_afrags(ns, nd, t + 2, mrow, quad, xb, xsb, efp, anext);
    }
}

// ---- per-node segment softmax + weighted gather -> bf16 agg
__global__ __launch_bounds__(256) void k_agg(
    const __bf16* __restrict__ xb, const int* __restrict__ offsets,
    const int2* __restrict__ csr,
    const float* __restrict__ raw, __bf16* __restrict__ aggb)
{
    int tid = threadIdx.x;
    int wave = tid >> 6, lane = tid & 63;
    int v = blockIdx.x * 4 + wave;
    if (v >= N_NODES_C) return;
    int s0 = offsets[v], s1 = offsets[v + 1];

    float m = -INFINITY;
    for (int p = s0 + lane; p < s1; p += 64) m = fmaxf(m, raw[p]);
#pragma unroll
    for (int off = 32; off > 0; off >>= 1) m = fmaxf(m, __shfl_xor(m, off, 64));

    float acc = 0.f, sum = 0.f;
    for (int p = s0; p < s1; ++p) {
        int src = csr[p].x;
        float w = expf(raw[p] - m);
        sum += w;
        acc += w * (float)xb[(long)src * 64 + lane];
    }
    aggb[(long)v * 64 + lane] = (__bf16)(acc / (sum + 1e-9f));
}

// ---- node update MLP via bf16 MFMA: one wave = 16 nodes
__global__ __launch_bounds__(256) void k_upd_mfma(
    const __bf16* __restrict__ xb, const __bf16* __restrict__ aggb,
    const __bf16* __restrict__ w1b, const float* __restrict__ b1,
    const __bf16* __restrict__ w2b, const float* __restrict__ b2,
    float* __restrict__ out)
{
    __shared__ __bf16 ubuf[4][16 * 136];
    int tid = threadIdx.x, wid = tid >> 6, lane = tid & 63;
    int tile = blockIdx.x * 4 + wid;
    if (tile >= UPD_TILES) return;
    int mrow = lane & 15, quad = lane >> 4;

    long node = (long)tile * 16 + mrow;
    bf16x8 a1[4];
    a1[0] = *(const bf16x8*)(xb + node * 64 + quad * 8);
    a1[1] = *(const bf16x8*)(xb + node * 64 + 32 + quad * 8);
    a1[2] = *(const bf16x8*)(aggb + node * 64 + quad * 8);
    a1[3] = *(const bf16x8*)(aggb + node * 64 + 32 + quad * 8);

    bf16x8 b1f[4][8];
#pragma unroll
    for (int ks = 0; ks < 4; ++ks)
#pragma unroll
        for (int nt = 0; nt < 8; ++nt)
            b1f[ks][nt] = *(const bf16x8*)(w1b + (long)(nt * 16 + mrow) * 128 + ks * 32 + quad * 8);

    f32x4 acc1[8];
#pragma unroll
    for (int nt = 0; nt < 8; ++nt) acc1[nt] = (f32x4){0.f, 0.f, 0.f, 0.f};
#pragma unroll
    for (int ks = 0; ks < 4; ++ks)
#pragma unroll
        for (int nt = 0; nt < 8; ++nt)
            acc1[nt] = __builtin_amdgcn_mfma_f32_16x16x32_bf16(a1[ks], b1f[ks][nt], acc1[nt], 0, 0, 0);

    __bf16* ub = ubuf[wid];
#pragma unroll
    for (int nt = 0; nt < 8; ++nt) {
        float bb = b1[nt * 16 + mrow];
#pragma unroll
        for (int r = 0; r < 4; ++r) {
            float h = fmaxf(acc1[nt][r] + bb, 0.f);
            ub[(quad * 4 + r) * 136 + nt * 16 + mrow] = (__bf16)h;
        }
    }

    bf16x8 a2[4];
#pragma unroll
    for (int ks = 0; ks < 4; ++ks)
        a2[ks] = *(bf16x8*)&ub[mrow * 136 + ks * 32 + quad * 8];

    bf16x8 b2f[4][4];
#pragma unroll
    for (int ks = 0; ks < 4; ++ks)
#pragma unroll
        for (int nt = 0; nt < 4; ++nt)
            b2f[ks][nt] = *(const bf16x8*)(w2b + (long)(nt * 16 + mrow) * 128 + ks * 32 + quad * 8);

    f32x4 acc2[4];
#pragma unroll
    for (int nt = 0; nt < 4; ++nt) acc2[nt] = (f32x4){0.f, 0.f, 0.f, 0.f};
#pragma unroll
    for (int ks = 0; ks < 4; ++ks)
#pragma unroll
        for (int nt = 0; nt < 4; ++nt)
            acc2[nt] = __builtin_amdgcn_mfma_f32_16x16x32_bf16(a2[ks], b2f[ks][nt], acc2[nt], 0, 0, 0);

#pragma unroll
    for (int nt = 0; nt < 4; ++nt) {
        float bb = b2[nt * 16 + mrow];
#pragma unroll
        for (int r = 0; r < 4; ++r) {
            long nodeo = (long)tile * 16 + quad * 4 + r;
            out[nodeo * 64 + nt * 16 + mrow] = fmaxf(acc2[nt][r] + bb, 0.f);
        }
    }
}

extern "C" void kernel_launch(void* const* d_in, const int* in_sizes, int n_in,
                              void* d_out, int out_size, void* d_ws, size_t ws_size,
                              hipStream_t stream) {
    const float* x    = (const float*)d_in[0];
    const float* xs   = (const float*)d_in[1];
    const int*   ei   = (const int*)d_in[2];
    const float* ef   = (const float*)d_in[3];
    const float* aw1  = (const float*)d_in[4];
    const float* ab1  = (const float*)d_in[5];
    const float* aw2  = (const float*)d_in[6];
    const float* ab2  = (const float*)d_in[7];
    const float* uw1  = (const float*)d_in[8];
    const float* ub1  = (const float*)d_in[9];
    const float* uw2  = (const float*)d_in[10];
    const float* ub2  = (const float*)d_in[11];
    float* out = (float*)d_out;

    char* ws = (char*)d_ws;
    float*  raw     = (float*)(ws + O_RAW);
    int*    deg     = (int*)(ws + O_DEG);
    int*    offsets = (int*)(ws + O_OFF);
    int*    cursor  = (int*)(ws + O_CUR);
    int2*   csr     = (int2*)(ws + O_CSR);
    __bf16* efp     = (__bf16*)(ws + O_EFP);
    __bf16* xb      = (__bf16*)(ws + O_XB);
    __bf16* xsb     = (__bf16*)(ws + O_XSB);
    __bf16* w1b     = (__bf16*)(ws + O_W1B);
    __bf16* uw1b    = (__bf16*)(ws + O_UW1B);
    __bf16* uw2b    = (__bf16*)(ws + O_UW2B);
    __bf16* aggb    = (__bf16*)(ws + O_AGGB);
    int*    psum    = (int*)(ws + O_PSUM);
    int*    boff    = (int*)(ws + O_BOFF);

    hipMemsetAsync(deg, 0, N_NODES_C * sizeof(int), stream);
    hipLaunchKernelGGL(k_deg,      dim3((E_C + 255) / 256),       dim3(256), 0, stream, ei, deg);
    hipLaunchKernelGGL(k_scan1,    dim3(SCAN_B),                  dim3(256), 0, stream, deg, psum);
    hipLaunchKernelGGL(k_scan2,    dim3(1),                       dim3(128), 0, stream, psum, boff, offsets);
    hipLaunchKernelGGL(k_scan3,    dim3(SCAN_B),                  dim3(256), 0, stream, deg, boff, offsets, cursor);
    hipLaunchKernelGGL(k_fill,     dim3((E_C + 255) / 256),       dim3(256), 0, stream,
                       ei, ef, cursor, csr, efp);
    hipLaunchKernelGGL(k_cvt,      dim3(1978),                    dim3(256), 0, stream,
                       x, xs, aw1, uw1, uw2, xb, xsb, w1b, uw1b, uw2b);
    hipLaunchKernelGGL(k_scores_mfma, dim3(SC_BLOCKS),            dim3(256), 0, stream,
                       xb, xsb, efp, w1b, csr, ab1, aw2, ab2, raw);
    hipLaunchKernelGGL(k_agg,      dim3((N_NODES_C + 3) / 4),     dim3(256), 0, stream,
                       xb, offsets, csr, raw, aggb);
    hipLaunchKernelGGL(k_upd_mfma, dim3((UPD_TILES + 3) / 4),     dim3(256), 0, stream,
                       xb, aggb, uw1b, ub1, uw2b, ub2, out);
}

// Round 6
// 415.032 us; speedup vs baseline: 1.2935x; 1.2935x over previous
//
#include <hip/hip_runtime.h>
#include <math.h>

#define N_NODES_C 50000
#define E_C       800000
#define ATT_IN_C  176
#define ATT_HID_C 144
#define SCAN_B    98      // ceil(50000 / 512)
#define UPD_TILES 3125    // 50000 / 16 exact
#define SC_BLOCKS 512     // 2048 waves = 2 waves/SIMD (VGPR=180 fits 2 naturally)

typedef __attribute__((ext_vector_type(8))) __bf16 bf16x8;
typedef __attribute__((ext_vector_type(4))) float f32x4;

// workspace layout (bytes, 1KB aligned)
#define O_RAW   0L          // float[E]
#define O_DEG   3201024L    // int[N]
#define O_OFF   3402752L    // int[N+1]
#define O_CUR   3603456L    // int[N]
#define O_CSR   3804160L    // int2[E] (src,dst) per CSR slot
#define O_EFP   10206208L   // bf16[E*16] permuted edge features
#define O_XB    35807232L   // bf16[N*64]
#define O_XSB   42208256L   // bf16[N*16]
#define O_W1B   43809280L   // bf16[144*176]
#define O_UW1B  43860992L   // bf16[128*128]
#define O_UW2B  43894784L   // bf16[64*128]
#define O_AGGB  43912192L   // bf16[N*64]  (psum/boff borrow head; dead by k_agg)
#define O_PSUM  O_AGGB
#define O_BOFF  (O_AGGB + 512L)

__device__ __forceinline__ bf16x8 bzero8() {
    bf16x8 z;
#pragma unroll
    for (int i = 0; i < 8; ++i) z[i] = (__bf16)0.0f;
    return z;
}

__global__ __launch_bounds__(256) void k_deg(const int* __restrict__ ei, int* __restrict__ deg) {
    int e = blockIdx.x * blockDim.x + threadIdx.x;
    if (e < E_C) atomicAdd(&deg[ei[E_C + e]], 1);
}

// ---- 3-phase parallel scan of deg -> offsets/cursor
__global__ __launch_bounds__(256) void k_scan1(const int* __restrict__ deg,
                                               int* __restrict__ psum) {
    __shared__ int red[256];
    int b = blockIdx.x, t = threadIdx.x;
    int i = b * 512 + t * 2;
    int s = 0;
    if (i < N_NODES_C) s += deg[i];
    if (i + 1 < N_NODES_C) s += deg[i + 1];
    red[t] = s;
    __syncthreads();
#pragma unroll
    for (int off = 128; off > 0; off >>= 1) {
        if (t < off) red[t] += red[t + off];
        __syncthreads();
    }
    if (t == 0) psum[b] = red[0];
}

__global__ __launch_bounds__(128) void k_scan2(const int* __restrict__ psum,
                                               int* __restrict__ boff,
                                               int* __restrict__ offsets) {
    __shared__ int sc[128];
    int t = threadIdx.x;
    int v = (t < SCAN_B) ? psum[t] : 0;
    sc[t] = v;
    __syncthreads();
#pragma unroll
    for (int off = 1; off < 128; off <<= 1) {
        int val = sc[t];
        int add = (t >= off) ? sc[t - off] : 0;
        __syncthreads();
        sc[t] = val + add;
        __syncthreads();
    }
    boff[t] = sc[t] - v;
    if (t == SCAN_B - 1) offsets[N_NODES_C] = sc[t];
}

__global__ __launch_bounds__(256) void k_scan3(const int* __restrict__ deg,
                                               const int* __restrict__ boff,
                                               int* __restrict__ offsets,
                                               int* __restrict__ cursor) {
    __shared__ int sc[256];
    int b = blockIdx.x, t = threadIdx.x;
    int i = b * 512 + t * 2;
    int d0 = (i < N_NODES_C) ? deg[i] : 0;
    int d1 = (i + 1 < N_NODES_C) ? deg[i + 1] : 0;
    int s = d0 + d1;
    sc[t] = s;
    __syncthreads();
#pragma unroll
    for (int off = 1; off < 256; off <<= 1) {
        int val = sc[t];
        int add = (t >= off) ? sc[t - off] : 0;
        __syncthreads();
        sc[t] = val + add;
        __syncthreads();
    }
    int excl = boff[b] + sc[t] - s;
    if (i < N_NODES_C)     { offsets[i]     = excl;      cursor[i]     = excl; }
    if (i + 1 < N_NODES_C) { offsets[i + 1] = excl + d0; cursor[i + 1] = excl + d0; }
}

// ---- CSR fill + ef permute/convert
__global__ __launch_bounds__(256) void k_fill(const int* __restrict__ ei,
                                              const float* __restrict__ ef,
                                              int* __restrict__ cursor,
                                              int2* __restrict__ csr,
                                              __bf16* __restrict__ efp) {
    int e = blockIdx.x * blockDim.x + threadIdx.x;
    if (e < E_C) {
        int src  = ei[e];
        int dst  = ei[E_C + e];
        int slot = atomicAdd(&cursor[dst], 1);
        csr[slot] = make_int2(src, dst);
        const float4* pe = (const float4*)(ef + (long)e * 16);
        float4 f0 = pe[0], f1 = pe[1], f2 = pe[2], f3 = pe[3];
        bf16x8 o0, o1;
        o0[0] = (__bf16)f0.x; o0[1] = (__bf16)f0.y; o0[2] = (__bf16)f0.z; o0[3] = (__bf16)f0.w;
        o0[4] = (__bf16)f1.x; o0[5] = (__bf16)f1.y; o0[6] = (__bf16)f1.z; o0[7] = (__bf16)f1.w;
        o1[0] = (__bf16)f2.x; o1[1] = (__bf16)f2.y; o1[2] = (__bf16)f2.z; o1[3] = (__bf16)f2.w;
        o1[4] = (__bf16)f3.x; o1[5] = (__bf16)f3.y; o1[6] = (__bf16)f3.z; o1[7] = (__bf16)f3.w;
        *(bf16x8*)(efp + (long)slot * 16)     = o0;
        *(bf16x8*)(efp + (long)slot * 16 + 8) = o1;
    }
}

// ---- fp32 -> bf16 conversion: x, xs, att_w1, upd_w1, upd_w2
__global__ __launch_bounds__(256) void k_cvt(
    const float* __restrict__ x, const float* __restrict__ xs,
    const float* __restrict__ w1, const float* __restrict__ uw1,
    const float* __restrict__ uw2,
    __bf16* __restrict__ xb, __bf16* __restrict__ xsb,
    __bf16* __restrict__ w1b, __bf16* __restrict__ uw1b,
    __bf16* __restrict__ uw2b)
{
    long g = (long)blockIdx.x * 256 + threadIdx.x;  // one group = 8 floats
    const long G_X = 400000, G_XS = 500000, G_W1 = 503168, G_UW1 = 505216, G_UW2 = 506240;
    if (g >= G_UW2) return;
    const float* src; __bf16* dst; long off;
    if (g < G_X)        { src = x;   dst = xb;   off = g * 8; }
    else if (g < G_XS)  { src = xs;  dst = xsb;  off = (g - G_X) * 8; }
    else if (g < G_W1)  { src = w1;  dst = w1b;  off = (g - G_XS) * 8; }
    else if (g < G_UW1) { src = uw1; dst = uw1b; off = (g - G_W1) * 8; }
    else                { src = uw2; dst = uw2b; off = (g - G_UW1) * 8; }
    float4 a = *(const float4*)(src + off);
    float4 b = *(const float4*)(src + off + 4);
    bf16x8 o;
    o[0] = (__bf16)a.x; o[1] = (__bf16)a.y; o[2] = (__bf16)a.z; o[3] = (__bf16)a.w;
    o[4] = (__bf16)b.x; o[5] = (__bf16)b.y; o[6] = (__bf16)b.z; o[7] = (__bf16)b.w;
    *(bf16x8*)(dst + off) = o;
}

// ---- A-fragment gather (CSR order: p = t*16 + mrow; efp contiguous)
__device__ __forceinline__ void load_afrags(
    int src, int dst, long t, int mrow, int quad,
    const __bf16* __restrict__ xb, const __bf16* __restrict__ xsb,
    const __bf16* __restrict__ efp,
    bf16x8 a[6])
{
    long p = t * 16 + mrow;
    const __bf16* px = xb + (long)src * 64 + quad * 8;
    const __bf16* pd = xb + (long)dst * 64 + quad * 8;
    a[0] = *(const bf16x8*)(px);
    a[1] = *(const bf16x8*)(px + 32);
    a[2] = *(const bf16x8*)(pd);
    a[3] = *(const bf16x8*)(pd + 32);
    if (quad < 2) {
        a[4] = *(const bf16x8*)(xsb + (long)src * 16 + quad * 8);
        a[5] = *(const bf16x8*)(efp + p * 16 + quad * 8);
    } else {
        a[4] = *(const bf16x8*)(xsb + (long)dst * 16 + (quad - 2) * 8);
        a[5] = bzero8();
    }
}

// ---- edge attention MLP via bf16 MFMA, CSR-ordered
// NOTE: no min-waves in launch_bounds! (256,2) forced VGPR=128 and spilled the
// 216-VGPR B-fragment array to scratch (FETCH 67->630MB, 99->233us, round 5).
// At the natural 180 VGPRs, 2 waves/SIMD fit in HW; grid=512 blocks supplies them.
__global__ __launch_bounds__(256) void k_scores_mfma(
    const __bf16* __restrict__ xb, const __bf16* __restrict__ xsb,
    const __bf16* __restrict__ efp, const __bf16* __restrict__ w1b,
    const int2* __restrict__ csr,
    const float* __restrict__ b1, const float* __restrict__ w2,
    const float* __restrict__ b2, float* __restrict__ raw)
{
    int tid  = threadIdx.x;
    int lane = tid & 63;
    int w    = blockIdx.x * 4 + (tid >> 6);   // global wave 0..2047
    const int NT = E_C / 16;
    const int TOT_W = SC_BLOCKS * 4;
    int per = (NT + TOT_W - 1) / TOT_W;       // 25
    long t0 = (long)w * per;
    long t1 = t0 + per; if (t1 > NT) t1 = NT;
    if (t0 >= t1) return;

    int mrow = lane & 15;
    int quad = lane >> 4;

    bf16x8 bfr[6][9];
#pragma unroll
    for (int ks = 0; ks < 6; ++ks) {
        int k0 = ks * 32 + quad * 8;
#pragma unroll
        for (int nt = 0; nt < 9; ++nt) {
            int n = nt * 16 + mrow;
            if (k0 + 8 <= ATT_IN_C)
                bfr[ks][nt] = *(const bf16x8*)(w1b + (long)n * ATT_IN_C + k0);
            else
                bfr[ks][nt] = bzero8();
        }
    }

    float b1v[9], w2v[9];
#pragma unroll
    for (int nt = 0; nt < 9; ++nt) {
        int n = nt * 16 + mrow;
        b1v[nt] = b1[n];
        w2v[nt] = w2[n];
    }
    float b2v = b2[0];

    bf16x8 acur[6], anext[6];
    int ns = 0, nd = 0;
    {
        int2 c0 = csr[t0 * 16 + mrow];
        load_afrags(c0.x, c0.y, t0, mrow, quad, xb, xsb, efp, acur);
        if (t0 + 1 < t1) {
            int2 c1 = csr[(t0 + 1) * 16 + mrow];
            load_afrags(c1.x, c1.y, t0 + 1, mrow, quad, xb, xsb, efp, anext);
        }
    }

    for (long t = t0; t < t1; ++t) {
        if (t + 2 < t1) {
            int2 c2 = csr[(t + 2) * 16 + mrow];
            ns = c2.x;
            nd = c2.y;
        }

        f32x4 acc[9];
#pragma unroll
        for (int nt = 0; nt < 9; ++nt) acc[nt] = (f32x4){0.f, 0.f, 0.f, 0.f};

#pragma unroll
        for (int ks = 0; ks < 6; ++ks) {
#pragma unroll
            for (int nt = 0; nt < 9; ++nt) {
                acc[nt] = __builtin_amdgcn_mfma_f32_16x16x32_bf16(
                    acur[ks], bfr[ks][nt], acc[nt], 0, 0, 0);
            }
        }

        float p0 = 0.f, p1 = 0.f, p2 = 0.f, p3 = 0.f;
#pragma unroll
        for (int nt = 0; nt < 9; ++nt) {
            p0 += w2v[nt] * fmaxf(acc[nt][0] + b1v[nt], 0.f);
            p1 += w2v[nt] * fmaxf(acc[nt][1] + b1v[nt], 0.f);
            p2 += w2v[nt] * fmaxf(acc[nt][2] + b1v[nt], 0.f);
            p3 += w2v[nt] * fmaxf(acc[nt][3] + b1v[nt], 0.f);
        }
#pragma unroll
        for (int off = 1; off < 16; off <<= 1) {
            p0 += __shfl_xor(p0, off, 64);
            p1 += __shfl_xor(p1, off, 64);
            p2 += __shfl_xor(p2, off, 64);
            p3 += __shfl_xor(p3, off, 64);
        }
        if (mrow < 4) {
            float v = (mrow == 0) ? p0 : (mrow == 1) ? p1 : (mrow == 2) ? p2 : p3;
            v += b2v;
            v = (v >= 0.f) ? v : 0.01f * v;
            raw[t * 16 + quad * 4 + mrow] = v;
        }

#pragma unroll
        for (int i = 0; i < 6; ++i) acur[i] = anext[i];
        if (t + 2 < t1)
            load_afrags(ns, nd, t + 2, mrow, quad, xb, xsb, efp, anext);
    }
}

// ---- per-node segment softmax + weighted gather -> bf16 agg
__global__ __launch_bounds__(256) void k_agg(
    const __bf16* __restrict__ xb, const int* __restrict__ offsets,
    const int2* __restrict__ csr,
    const float* __restrict__ raw, __bf16* __restrict__ aggb)
{
    int tid = threadIdx.x;
    int wave = tid >> 6, lane = tid & 63;
    int v = blockIdx.x * 4 + wave;
    if (v >= N_NODES_C) return;
    int s0 = offsets[v], s1 = offsets[v + 1];

    float m = -INFINITY;
    for (int p = s0 + lane; p < s1; p += 64) m = fmaxf(m, raw[p]);
#pragma unroll
    for (int off = 32; off > 0; off >>= 1) m = fmaxf(m, __shfl_xor(m, off, 64));

    float acc = 0.f, sum = 0.f;
    for (int p = s0; p < s1; ++p) {
        int src = csr[p].x;
        float w = expf(raw[p] - m);
        sum += w;
        acc += w * (float)xb[(long)src * 64 + lane];
    }
    aggb[(long)v * 64 + lane] = (__bf16)(acc / (sum + 1e-9f));
}

// ---- node update MLP via bf16 MFMA: one wave = 16 nodes
__global__ __launch_bounds__(256) void k_upd_mfma(
    const __bf16* __restrict__ xb, const __bf16* __restrict__ aggb,
    const __bf16* __restrict__ w1b, const float* __restrict__ b1,
    const __bf16* __restrict__ w2b, const float* __restrict__ b2,
    float* __restrict__ out)
{
    __shared__ __bf16 ubuf[4][16 * 136];
    int tid = threadIdx.x, wid = tid >> 6, lane = tid & 63;
    int tile = blockIdx.x * 4 + wid;
    if (tile >= UPD_TILES) return;
    int mrow = lane & 15, quad = lane >> 4;

    long node = (long)tile * 16 + mrow;
    bf16x8 a1[4];
    a1[0] = *(const bf16x8*)(xb + node * 64 + quad * 8);
    a1[1] = *(const bf16x8*)(xb + node * 64 + 32 + quad * 8);
    a1[2] = *(const bf16x8*)(aggb + node * 64 + quad * 8);
    a1[3] = *(const bf16x8*)(aggb + node * 64 + 32 + quad * 8);

    bf16x8 b1f[4][8];
#pragma unroll
    for (int ks = 0; ks < 4; ++ks)
#pragma unroll
        for (int nt = 0; nt < 8; ++nt)
            b1f[ks][nt] = *(const bf16x8*)(w1b + (long)(nt * 16 + mrow) * 128 + ks * 32 + quad * 8);

    f32x4 acc1[8];
#pragma unroll
    for (int nt = 0; nt < 8; ++nt) acc1[nt] = (f32x4){0.f, 0.f, 0.f, 0.f};
#pragma unroll
    for (int ks = 0; ks < 4; ++ks)
#pragma unroll
        for (int nt = 0; nt < 8; ++nt)
            acc1[nt] = __builtin_amdgcn_mfma_f32_16x16x32_bf16(a1[ks], b1f[ks][nt], acc1[nt], 0, 0, 0);

    __bf16* ub = ubuf[wid];
#pragma unroll
    for (int nt = 0; nt < 8; ++nt) {
        float bb = b1[nt * 16 + mrow];
#pragma unroll
        for (int r = 0; r < 4; ++r) {
            float h = fmaxf(acc1[nt][r] + bb, 0.f);
            ub[(quad * 4 + r) * 136 + nt * 16 + mrow] = (__bf16)h;
        }
    }

    bf16x8 a2[4];
#pragma unroll
    for (int ks = 0; ks < 4; ++ks)
        a2[ks] = *(bf16x8*)&ub[mrow * 136 + ks * 32 + quad * 8];

    bf16x8 b2f[4][4];
#pragma unroll
    for (int ks = 0; ks < 4; ++ks)
#pragma unroll
        for (int nt = 0; nt < 4; ++nt)
            b2f[ks][nt] = *(const bf16x8*)(w2b + (long)(nt * 16 + mrow) * 128 + ks * 32 + quad * 8);

    f32x4 acc2[4];
#pragma unroll
    for (int nt = 0; nt < 4; ++nt) acc2[nt] = (f32x4){0.f, 0.f, 0.f, 0.f};
#pragma unroll
    for (int ks = 0; ks < 4; ++ks)
#pragma unroll
        for (int nt = 0; nt < 4; ++nt)
            acc2[nt] = __builtin_amdgcn_mfma_f32_16x16x32_bf16(a2[ks], b2f[ks][nt], acc2[nt], 0, 0, 0);

#pragma unroll
    for (int nt = 0; nt < 4; ++nt) {
        float bb = b2[nt * 16 + mrow];
#pragma unroll
        for (int r = 0; r < 4; ++r) {
            long nodeo = (long)tile * 16 + quad * 4 + r;
            out[nodeo * 64 + nt * 16 + mrow] = fmaxf(acc2[nt][r] + bb, 0.f);
        }
    }
}

extern "C" void kernel_launch(void* const* d_in, const int* in_sizes, int n_in,
                              void* d_out, int out_size, void* d_ws, size_t ws_size,
                              hipStream_t stream) {
    const float* x    = (const float*)d_in[0];
    const float* xs   = (const float*)d_in[1];
    const int*   ei   = (const int*)d_in[2];
    const float* ef   = (const float*)d_in[3];
    const float* aw1  = (const float*)d_in[4];
    const float* ab1  = (const float*)d_in[5];
    const float* aw2  = (const float*)d_in[6];
    const float* ab2  = (const float*)d_in[7];
    const float* uw1  = (const float*)d_in[8];
    const float* ub1  = (const float*)d_in[9];
    const float* uw2  = (const float*)d_in[10];
    const float* ub2  = (const float*)d_in[11];
    float* out = (float*)d_out;

    char* ws = (char*)d_ws;
    float*  raw     = (float*)(ws + O_RAW);
    int*    deg     = (int*)(ws + O_DEG);
    int*    offsets = (int*)(ws + O_OFF);
    int*    cursor  = (int*)(ws + O_CUR);
    int2*   csr     = (int2*)(ws + O_CSR);
    __bf16* efp     = (__bf16*)(ws + O_EFP);
    __bf16* xb      = (__bf16*)(ws + O_XB);
    __bf16* xsb     = (__bf16*)(ws + O_XSB);
    __bf16* w1b     = (__bf16*)(ws + O_W1B);
    __bf16* uw1b    = (__bf16*)(ws + O_UW1B);
    __bf16* uw2b    = (__bf16*)(ws + O_UW2B);
    __bf16* aggb    = (__bf16*)(ws + O_AGGB);
    int*    psum    = (int*)(ws + O_PSUM);
    int*    boff    = (int*)(ws + O_BOFF);

    hipMemsetAsync(deg, 0, N_NODES_C * sizeof(int), stream);
    hipLaunchKernelGGL(k_deg,      dim3((E_C + 255) / 256),       dim3(256), 0, stream, ei, deg);
    hipLaunchKernelGGL(k_scan1,    dim3(SCAN_B),                  dim3(256), 0, stream, deg, psum);
    hipLaunchKernelGGL(k_scan2,    dim3(1),                       dim3(128), 0, stream, psum, boff, offsets);
    hipLaunchKernelGGL(k_scan3,    dim3(SCAN_B),                  dim3(256), 0, stream, deg, boff, offsets, cursor);
    hipLaunchKernelGGL(k_fill,     dim3((E_C + 255) / 256),       dim3(256), 0, stream,
                       ei, ef, cursor, csr, efp);
    hipLaunchKernelGGL(k_cvt,      dim3(1978),                    dim3(256), 0, stream,
                       x, xs, aw1, uw1, uw2, xb, xsb, w1b, uw1b, uw2b);
    hipLaunchKernelGGL(k_scores_mfma, dim3(SC_BLOCKS),            dim3(256), 0, stream,
                       xb, xsb, efp, w1b, csr, ab1, aw2, ab2, raw);
    hipLaunchKernelGGL(k_agg,      dim3((N_NODES_C + 3) / 4),     dim3(256), 0, stream,
                       xb, offsets, csr, raw, aggb);
    hipLaunchKernelGGL(k_upd_mfma, dim3((UPD_TILES + 3) / 4),     dim3(256), 0, stream,
                       xb, aggb, uw1b, ub1, uw2b, ub2, out);
}

// Round 7
// 400.888 us; speedup vs baseline: 1.3392x; 1.0353x over previous
//
#include <hip/hip_runtime.h>
#include <math.h>

#define N_NODES_C 50000
#define E_C       800000
#define ATT_IN_C  176
#define ATT_HID_C 144
#define SCAN_B    98      // ceil(50000 / 512)
#define UPD_TILES 3125    // 50000 / 16 exact

typedef __attribute__((ext_vector_type(8))) __bf16 bf16x8;
typedef __attribute__((ext_vector_type(4))) float f32x4;

// workspace layout (bytes, 1KB aligned)
#define O_RAW   0L          // float[E]
#define O_DEG   3201024L    // int[N]
#define O_OFF   3402752L    // int[N+1]
#define O_CUR   3603456L    // int[N]
#define O_CSR   3804160L    // int4[E] (src,dst,e,-) per CSR slot   12.8MB
#define O_EFB   16605184L   // bf16[E*16] edge features, ORIGINAL order  25.6MB
#define O_XB    42206208L   // bf16[N*64]
#define O_XSB   48607232L   // bf16[N*16]
#define O_W1B   50208256L   // bf16[144*176]
#define O_UW1B  50259968L   // bf16[128*128]
#define O_UW2B  50293760L   // bf16[64*128]
#define O_AGGB  50311168L   // bf16[N*64]  (psum/boff borrow head; dead by k_agg)
#define O_PSUM  O_AGGB
#define O_BOFF  (O_AGGB + 512L)

__device__ __forceinline__ bf16x8 bzero8() {
    bf16x8 z;
#pragma unroll
    for (int i = 0; i < 8; ++i) z[i] = (__bf16)0.0f;
    return z;
}

__global__ __launch_bounds__(256) void k_deg(const int* __restrict__ ei, int* __restrict__ deg) {
    int e = blockIdx.x * blockDim.x + threadIdx.x;
    if (e < E_C) atomicAdd(&deg[ei[E_C + e]], 1);
}

// ---- 3-phase parallel scan of deg -> offsets/cursor
__global__ __launch_bounds__(256) void k_scan1(const int* __restrict__ deg,
                                               int* __restrict__ psum) {
    __shared__ int red[256];
    int b = blockIdx.x, t = threadIdx.x;
    int i = b * 512 + t * 2;
    int s = 0;
    if (i < N_NODES_C) s += deg[i];
    if (i + 1 < N_NODES_C) s += deg[i + 1];
    red[t] = s;
    __syncthreads();
#pragma unroll
    for (int off = 128; off > 0; off >>= 1) {
        if (t < off) red[t] += red[t + off];
        __syncthreads();
    }
    if (t == 0) psum[b] = red[0];
}

__global__ __launch_bounds__(128) void k_scan2(const int* __restrict__ psum,
                                               int* __restrict__ boff,
                                               int* __restrict__ offsets) {
    __shared__ int sc[128];
    int t = threadIdx.x;
    int v = (t < SCAN_B) ? psum[t] : 0;
    sc[t] = v;
    __syncthreads();
#pragma unroll
    for (int off = 1; off < 128; off <<= 1) {
        int val = sc[t];
        int add = (t >= off) ? sc[t - off] : 0;
        __syncthreads();
        sc[t] = val + add;
        __syncthreads();
    }
    boff[t] = sc[t] - v;
    if (t == SCAN_B - 1) offsets[N_NODES_C] = sc[t];
}

__global__ __launch_bounds__(256) void k_scan3(const int* __restrict__ deg,
                                               const int* __restrict__ boff,
                                               int* __restrict__ offsets,
                                               int* __restrict__ cursor) {
    __shared__ int sc[256];
    int b = blockIdx.x, t = threadIdx.x;
    int i = b * 512 + t * 2;
    int d0 = (i < N_NODES_C) ? deg[i] : 0;
    int d1 = (i + 1 < N_NODES_C) ? deg[i + 1] : 0;
    int s = d0 + d1;
    sc[t] = s;
    __syncthreads();
#pragma unroll
    for (int off = 1; off < 256; off <<= 1) {
        int val = sc[t];
        int add = (t >= off) ? sc[t - off] : 0;
        __syncthreads();
        sc[t] = val + add;
        __syncthreads();
    }
    int excl = boff[b] + sc[t] - s;
    if (i < N_NODES_C)     { offsets[i]     = excl;      cursor[i]     = excl; }
    if (i + 1 < N_NODES_C) { offsets[i + 1] = excl + d0; cursor[i + 1] = excl + d0; }
}

// ---- CSR fill: only (src,dst,e) records; no ef permutation (scattered 32B
// bf16 stores were RMW-amplified HBM writes — efb is gathered by e instead)
__global__ __launch_bounds__(256) void k_fill(const int* __restrict__ ei,
                                              int* __restrict__ cursor,
                                              int4* __restrict__ csr) {
    int e = blockIdx.x * blockDim.x + threadIdx.x;
    if (e < E_C) {
        int src  = ei[e];
        int dst  = ei[E_C + e];
        int slot = atomicAdd(&cursor[dst], 1);
        csr[slot] = make_int4(src, dst, e, 0);
    }
}

// ---- fp32 -> bf16 conversion: x, xs, ef, att_w1, upd_w1, upd_w2 (all coalesced)
__global__ __launch_bounds__(256) void k_cvt(
    const float* __restrict__ x, const float* __restrict__ xs,
    const float* __restrict__ ef, const float* __restrict__ w1,
    const float* __restrict__ uw1, const float* __restrict__ uw2,
    __bf16* __restrict__ xb, __bf16* __restrict__ xsb,
    __bf16* __restrict__ efb, __bf16* __restrict__ w1b,
    __bf16* __restrict__ uw1b, __bf16* __restrict__ uw2b)
{
    long g = (long)blockIdx.x * 256 + threadIdx.x;  // one group = 8 floats
    const long G_X = 400000, G_XS = 500000, G_EF = 2100000,
               G_W1 = 2103168, G_UW1 = 2105216, G_UW2 = 2106240;
    if (g >= G_UW2) return;
    const float* src; __bf16* dst; long off;
    if (g < G_X)        { src = x;   dst = xb;   off = g * 8; }
    else if (g < G_XS)  { src = xs;  dst = xsb;  off = (g - G_X) * 8; }
    else if (g < G_EF)  { src = ef;  dst = efb;  off = (g - G_XS) * 8; }
    else if (g < G_W1)  { src = w1;  dst = w1b;  off = (g - G_EF) * 8; }
    else if (g < G_UW1) { src = uw1; dst = uw1b; off = (g - G_W1) * 8; }
    else                { src = uw2; dst = uw2b; off = (g - G_UW1) * 8; }
    float4 a = *(const float4*)(src + off);
    float4 b = *(const float4*)(src + off + 4);
    bf16x8 o;
    o[0] = (__bf16)a.x; o[1] = (__bf16)a.y; o[2] = (__bf16)a.z; o[3] = (__bf16)a.w;
    o[4] = (__bf16)b.x; o[5] = (__bf16)b.y; o[6] = (__bf16)b.z; o[7] = (__bf16)b.w;
    *(bf16x8*)(dst + off) = o;
}

// ---- A-fragment gather (ef indexed by original edge id e)
__device__ __forceinline__ void load_afrags(
    int src, int dst, int e, int quad,
    const __bf16* __restrict__ xb, const __bf16* __restrict__ xsb,
    const __bf16* __restrict__ efb,
    bf16x8 a[6])
{
    const __bf16* px = xb + (long)src * 64 + quad * 8;
    const __bf16* pd = xb + (long)dst * 64 + quad * 8;
    a[0] = *(const bf16x8*)(px);
    a[1] = *(const bf16x8*)(px + 32);
    a[2] = *(const bf16x8*)(pd);
    a[3] = *(const bf16x8*)(pd + 32);
    if (quad < 2) {
        a[4] = *(const bf16x8*)(xsb + (long)src * 16 + quad * 8);
        a[5] = *(const bf16x8*)(efb + (long)e * 16 + quad * 8);
    } else {
        a[4] = *(const bf16x8*)(xsb + (long)dst * 16 + (quad - 2) * 8);
        a[5] = bzero8();
    }
}

// ---- edge attention MLP via bf16 MFMA, CSR-ordered, 2-tile ILP per iteration.
// Occupancy is hard-capped at 1 wave/SIMD by the unified VGPR+AGPR working set
// (~340 regs); (256,2) bound spills (round 5), extra blocks don't help (round 6).
// So: two independent 16-edge tiles per iteration = 2x MFMA chains + 2x MLP.
__global__ __launch_bounds__(256) void k_scores_mfma(
    const __bf16* __restrict__ xb, const __bf16* __restrict__ xsb,
    const __bf16* __restrict__ efb, const __bf16* __restrict__ w1b,
    const int4* __restrict__ csr,
    const float* __restrict__ b1, const float* __restrict__ w2,
    const float* __restrict__ b2, float* __restrict__ raw)
{
    int tid  = threadIdx.x;
    int lane = tid & 63;
    int w    = blockIdx.x * 4 + (tid >> 6);   // global wave 0..1023
    const int NP = E_C / 32;                  // 25000 edge-pairs
    int per = (NP + 1023) / 1024;             // 25
    long j0 = (long)w * per;
    long j1 = j0 + per; if (j1 > NP) j1 = NP;
    if (j0 >= j1) return;

    int mrow = lane & 15;
    int quad = lane >> 4;

    bf16x8 bfr[6][9];
#pragma unroll
    for (int ks = 0; ks < 6; ++ks) {
        int k0 = ks * 32 + quad * 8;
#pragma unroll
        for (int nt = 0; nt < 9; ++nt) {
            int n = nt * 16 + mrow;
            if (k0 + 8 <= ATT_IN_C)
                bfr[ks][nt] = *(const bf16x8*)(w1b + (long)n * ATT_IN_C + k0);
            else
                bfr[ks][nt] = bzero8();
        }
    }

    float b1v[9], w2v[9];
#pragma unroll
    for (int nt = 0; nt < 9; ++nt) {
        int n = nt * 16 + mrow;
        b1v[nt] = b1[n];
        w2v[nt] = w2[n];
    }
    float b2v = b2[0];

    bf16x8 curA[6], curB[6], nxtA[6], nxtB[6];
    int4 cA = make_int4(0, 0, 0, 0), cB = cA;
    {
        int4 e0 = csr[j0 * 32 + mrow];
        int4 e1 = csr[j0 * 32 + 16 + mrow];
        load_afrags(e0.x, e0.y, e0.z, quad, xb, xsb, efb, curA);
        load_afrags(e1.x, e1.y, e1.z, quad, xb, xsb, efb, curB);
        if (j0 + 1 < j1) {
            int4 f0 = csr[(j0 + 1) * 32 + mrow];
            int4 f1 = csr[(j0 + 1) * 32 + 16 + mrow];
            load_afrags(f0.x, f0.y, f0.z, quad, xb, xsb, efb, nxtA);
            load_afrags(f1.x, f1.y, f1.z, quad, xb, xsb, efb, nxtB);
        }
    }

    for (long j = j0; j < j1; ++j) {
        if (j + 2 < j1) {
            cA = csr[(j + 2) * 32 + mrow];
            cB = csr[(j + 2) * 32 + 16 + mrow];
        }

        f32x4 accA[9], accB[9];
#pragma unroll
        for (int nt = 0; nt < 9; ++nt) {
            accA[nt] = (f32x4){0.f, 0.f, 0.f, 0.f};
            accB[nt] = (f32x4){0.f, 0.f, 0.f, 0.f};
        }

#pragma unroll
        for (int ks = 0; ks < 6; ++ks) {
#pragma unroll
            for (int nt = 0; nt < 9; ++nt) {
                accA[nt] = __builtin_amdgcn_mfma_f32_16x16x32_bf16(
                    curA[ks], bfr[ks][nt], accA[nt], 0, 0, 0);
                accB[nt] = __builtin_amdgcn_mfma_f32_16x16x32_bf16(
                    curB[ks], bfr[ks][nt], accB[nt], 0, 0, 0);
            }
        }

        float pA0 = 0.f, pA1 = 0.f, pA2 = 0.f, pA3 = 0.f;
        float pB0 = 0.f, pB1 = 0.f, pB2 = 0.f, pB3 = 0.f;
#pragma unroll
        for (int nt = 0; nt < 9; ++nt) {
            pA0 += w2v[nt] * fmaxf(accA[nt][0] + b1v[nt], 0.f);
            pA1 += w2v[nt] * fmaxf(accA[nt][1] + b1v[nt], 0.f);
            pA2 += w2v[nt] * fmaxf(accA[nt][2] + b1v[nt], 0.f);
            pA3 += w2v[nt] * fmaxf(accA[nt][3] + b1v[nt], 0.f);
            pB0 += w2v[nt] * fmaxf(accB[nt][0] + b1v[nt], 0.f);
            pB1 += w2v[nt] * fmaxf(accB[nt][1] + b1v[nt], 0.f);
            pB2 += w2v[nt] * fmaxf(accB[nt][2] + b1v[nt], 0.f);
            pB3 += w2v[nt] * fmaxf(accB[nt][3] + b1v[nt], 0.f);
        }
#pragma unroll
        for (int off = 1; off < 16; off <<= 1) {
            pA0 += __shfl_xor(pA0, off, 64);
            pA1 += __shfl_xor(pA1, off, 64);
            pA2 += __shfl_xor(pA2, off, 64);
            pA3 += __shfl_xor(pA3, off, 64);
            pB0 += __shfl_xor(pB0, off, 64);
            pB1 += __shfl_xor(pB1, off, 64);
            pB2 += __shfl_xor(pB2, off, 64);
            pB3 += __shfl_xor(pB3, off, 64);
        }
        if (mrow < 4) {
            float vA = (mrow == 0) ? pA0 : (mrow == 1) ? pA1 : (mrow == 2) ? pA2 : pA3;
            float vB = (mrow == 0) ? pB0 : (mrow == 1) ? pB1 : (mrow == 2) ? pB2 : pB3;
            vA += b2v; vB += b2v;
            vA = (vA >= 0.f) ? vA : 0.01f * vA;
            vB = (vB >= 0.f) ? vB : 0.01f * vB;
            raw[(j * 2) * 16 + quad * 4 + mrow]     = vA;
            raw[(j * 2 + 1) * 16 + quad * 4 + mrow] = vB;
        }

#pragma unroll
        for (int i = 0; i < 6; ++i) { curA[i] = nxtA[i]; curB[i] = nxtB[i]; }
        if (j + 2 < j1) {
            load_afrags(cA.x, cA.y, cA.z, quad, xb, xsb, efb, nxtA);
            load_afrags(cB.x, cB.y, cB.z, quad, xb, xsb, efb, nxtB);
        }
    }
}

// ---- per-node segment softmax + weighted gather -> bf16 agg
__global__ __launch_bounds__(256) void k_agg(
    const __bf16* __restrict__ xb, const int* __restrict__ offsets,
    const int4* __restrict__ csr,
    const float* __restrict__ raw, __bf16* __restrict__ aggb)
{
    int tid = threadIdx.x;
    int wave = tid >> 6, lane = tid & 63;
    int v = blockIdx.x * 4 + wave;
    if (v >= N_NODES_C) return;
    int s0 = offsets[v], s1 = offsets[v + 1];

    float m = -INFINITY;
    for (int p = s0 + lane; p < s1; p += 64) m = fmaxf(m, raw[p]);
#pragma unroll
    for (int off = 32; off > 0; off >>= 1) m = fmaxf(m, __shfl_xor(m, off, 64));

    float acc = 0.f, sum = 0.f;
    for (int p = s0; p < s1; ++p) {
        int src = csr[p].x;
        float w = expf(raw[p] - m);
        sum += w;
        acc += w * (float)xb[(long)src * 64 + lane];
    }
    aggb[(long)v * 64 + lane] = (__bf16)(acc / (sum + 1e-9f));
}

// ---- node update MLP via bf16 MFMA: one wave = 16 nodes
__global__ __launch_bounds__(256) void k_upd_mfma(
    const __bf16* __restrict__ xb, const __bf16* __restrict__ aggb,
    const __bf16* __restrict__ w1b, const float* __restrict__ b1,
    const __bf16* __restrict__ w2b, const float* __restrict__ b2,
    float* __restrict__ out)
{
    __shared__ __bf16 ubuf[4][16 * 136];
    int tid = threadIdx.x, wid = tid >> 6, lane = tid & 63;
    int tile = blockIdx.x * 4 + wid;
    if (tile >= UPD_TILES) return;
    int mrow = lane & 15, quad = lane >> 4;

    long node = (long)tile * 16 + mrow;
    bf16x8 a1[4];
    a1[0] = *(const bf16x8*)(xb + node * 64 + quad * 8);
    a1[1] = *(const bf16x8*)(xb + node * 64 + 32 + quad * 8);
    a1[2] = *(const bf16x8*)(aggb + node * 64 + quad * 8);
    a1[3] = *(const bf16x8*)(aggb + node * 64 + 32 + quad * 8);

    bf16x8 b1f[4][8];
#pragma unroll
    for (int ks = 0; ks < 4; ++ks)
#pragma unroll
        for (int nt = 0; nt < 8; ++nt)
            b1f[ks][nt] = *(const bf16x8*)(w1b + (long)(nt * 16 + mrow) * 128 + ks * 32 + quad * 8);

    f32x4 acc1[8];
#pragma unroll
    for (int nt = 0; nt < 8; ++nt) acc1[nt] = (f32x4){0.f, 0.f, 0.f, 0.f};
#pragma unroll
    for (int ks = 0; ks < 4; ++ks)
#pragma unroll
        for (int nt = 0; nt < 8; ++nt)
            acc1[nt] = __builtin_amdgcn_mfma_f32_16x16x32_bf16(a1[ks], b1f[ks][nt], acc1[nt], 0, 0, 0);

    __bf16* ub = ubuf[wid];
#pragma unroll
    for (int nt = 0; nt < 8; ++nt) {
        float bb = b1[nt * 16 + mrow];
#pragma unroll
        for (int r = 0; r < 4; ++r) {
            float h = fmaxf(acc1[nt][r] + bb, 0.f);
            ub[(quad * 4 + r) * 136 + nt * 16 + mrow] = (__bf16)h;
        }
    }

    bf16x8 a2[4];
#pragma unroll
    for (int ks = 0; ks < 4; ++ks)
        a2[ks] = *(bf16x8*)&ub[mrow * 136 + ks * 32 + quad * 8];

    bf16x8 b2f[4][4];
#pragma unroll
    for (int ks = 0; ks < 4; ++ks)
#pragma unroll
        for (int nt = 0; nt < 4; ++nt)
            b2f[ks][nt] = *(const bf16x8*)(w2b + (long)(nt * 16 + mrow) * 128 + ks * 32 + quad * 8);

    f32x4 acc2[4];
#pragma unroll
    for (int nt = 0; nt < 4; ++nt) acc2[nt] = (f32x4){0.f, 0.f, 0.f, 0.f};
#pragma unroll
    for (int ks = 0; ks < 4; ++ks)
#pragma unroll
        for (int nt = 0; nt < 4; ++nt)
            acc2[nt] = __builtin_amdgcn_mfma_f32_16x16x32_bf16(a2[ks], b2f[ks][nt], acc2[nt], 0, 0, 0);

#pragma unroll
    for (int nt = 0; nt < 4; ++nt) {
        float bb = b2[nt * 16 + mrow];
#pragma unroll
        for (int r = 0; r < 4; ++r) {
            long nodeo = (long)tile * 16 + quad * 4 + r;
            out[nodeo * 64 + nt * 16 + mrow] = fmaxf(acc2[nt][r] + bb, 0.f);
        }
    }
}

extern "C" void kernel_launch(void* const* d_in, const int* in_sizes, int n_in,
                              void* d_out, int out_size, void* d_ws, size_t ws_size,
                              hipStream_t stream) {
    const float* x    = (const float*)d_in[0];
    const float* xs   = (const float*)d_in[1];
    const int*   ei   = (const int*)d_in[2];
    const float* ef   = (const float*)d_in[3];
    const float* aw1  = (const float*)d_in[4];
    const float* ab1  = (const float*)d_in[5];
    const float* aw2  = (const float*)d_in[6];
    const float* ab2  = (const float*)d_in[7];
    const float* uw1  = (const float*)d_in[8];
    const float* ub1  = (const float*)d_in[9];
    const float* uw2  = (const float*)d_in[10];
    const float* ub2  = (const float*)d_in[11];
    float* out = (float*)d_out;

    char* ws = (char*)d_ws;
    float*  raw     = (float*)(ws + O_RAW);
    int*    deg     = (int*)(ws + O_DEG);
    int*    offsets = (int*)(ws + O_OFF);
    int*    cursor  = (int*)(ws + O_CUR);
    int4*   csr     = (int4*)(ws + O_CSR);
    __bf16* efb     = (__bf16*)(ws + O_EFB);
    __bf16* xb      = (__bf16*)(ws + O_XB);
    __bf16* xsb     = (__bf16*)(ws + O_XSB);
    __bf16* w1b     = (__bf16*)(ws + O_W1B);
    __bf16* uw1b    = (__bf16*)(ws + O_UW1B);
    __bf16* uw2b    = (__bf16*)(ws + O_UW2B);
    __bf16* aggb    = (__bf16*)(ws + O_AGGB);
    int*    psum    = (int*)(ws + O_PSUM);
    int*    boff    = (int*)(ws + O_BOFF);

    hipMemsetAsync(deg, 0, N_NODES_C * sizeof(int), stream);
    hipLaunchKernelGGL(k_deg,      dim3((E_C + 255) / 256),       dim3(256), 0, stream, ei, deg);
    hipLaunchKernelGGL(k_scan1,    dim3(SCAN_B),                  dim3(256), 0, stream, deg, psum);
    hipLaunchKernelGGL(k_scan2,    dim3(1),                       dim3(128), 0, stream, psum, boff, offsets);
    hipLaunchKernelGGL(k_scan3,    dim3(SCAN_B),                  dim3(256), 0, stream, deg, boff, offsets, cursor);
    hipLaunchKernelGGL(k_fill,     dim3((E_C + 255) / 256),       dim3(256), 0, stream,
                       ei, cursor, csr);
    hipLaunchKernelGGL(k_cvt,      dim3(8228),                    dim3(256), 0, stream,
                       x, xs, ef, aw1, uw1, uw2, xb, xsb, efb, w1b, uw1b, uw2b);
    hipLaunchKernelGGL(k_scores_mfma, dim3(256),                  dim3(256), 0, stream,
                       xb, xsb, efb, w1b, csr, ab1, aw2, ab2, raw);
    hipLaunchKernelGGL(k_agg,      dim3((N_NODES_C + 3) / 4),     dim3(256), 0, stream,
                       xb, offsets, csr, raw, aggb);
    hipLaunchKernelGGL(k_upd_mfma, dim3((UPD_TILES + 3) / 4),     dim3(256), 0, stream,
                       xb, aggb, uw1b, ub1, uw2b, ub2, out);
}

// Round 8
// 354.902 us; speedup vs baseline: 1.5127x; 1.1296x over previous
//
#include <hip/hip_runtime.h>
#include <math.h>

#define N_NODES_C 50000
#define E_C       800000
#define ATT_IN_C  176
#define ATT_HID_C 144
#define SCAN_B    98      // ceil(50000 / 512)
#define UPD_TILES 3125    // 50000 / 16 exact
#define DEG_B     3125    // 800000 / 256 exact
#define CVT_B     8228

typedef __attribute__((ext_vector_type(8))) __bf16 bf16x8;
typedef __attribute__((ext_vector_type(4))) float f32x4;

// workspace layout (bytes, 1KB aligned)
#define O_RAW   0L          // float[E]
#define O_DEG   3201024L    // int[N]
#define O_OFF   3402752L    // int[N+1]
#define O_CUR   3603456L    // int[N]
#define O_CSR   3804160L    // int4[E] (src,dst,e,-) per CSR slot
#define O_EFB   16605184L   // bf16[E*16] edge features, original order
#define O_XB    42206208L   // bf16[N*64]
#define O_XSB   48607232L   // bf16[N*16]
#define O_W1B   50208256L   // bf16[144*176]
#define O_UW1B  50259968L   // bf16[128*128]
#define O_UW2B  50293760L   // bf16[64*128]
#define O_AGGB  50311168L   // bf16[N*64]  (psum borrows head; dead by k_agg)
#define O_PSUM  O_AGGB

__device__ __forceinline__ bf16x8 bzero8() {
    bf16x8 z;
#pragma unroll
    for (int i = 0; i < 8; ++i) z[i] = (__bf16)0.0f;
    return z;
}

// ---- fused: degree count (blocks 0..DEG_B) + fp32->bf16 convert (rest)
__global__ __launch_bounds__(256) void k_prep(
    const int* __restrict__ ei,
    const float* __restrict__ x, const float* __restrict__ xs,
    const float* __restrict__ ef, const float* __restrict__ w1,
    const float* __restrict__ uw1, const float* __restrict__ uw2,
    int* __restrict__ deg,
    __bf16* __restrict__ xb, __bf16* __restrict__ xsb,
    __bf16* __restrict__ efb, __bf16* __restrict__ w1b,
    __bf16* __restrict__ uw1b, __bf16* __restrict__ uw2b)
{
    int bid = blockIdx.x;
    if (bid < DEG_B) {
        int e = bid * 256 + threadIdx.x;
        if (e < E_C) atomicAdd(&deg[ei[E_C + e]], 1);
        return;
    }
    long g = (long)(bid - DEG_B) * 256 + threadIdx.x;  // one group = 8 floats
    const long G_X = 400000, G_XS = 500000, G_EF = 2100000,
               G_W1 = 2103168, G_UW1 = 2105216, G_UW2 = 2106240;
    if (g >= G_UW2) return;
    const float* src; __bf16* dst; long off;
    if (g < G_X)        { src = x;   dst = xb;   off = g * 8; }
    else if (g < G_XS)  { src = xs;  dst = xsb;  off = (g - G_X) * 8; }
    else if (g < G_EF)  { src = ef;  dst = efb;  off = (g - G_XS) * 8; }
    else if (g < G_W1)  { src = w1;  dst = w1b;  off = (g - G_EF) * 8; }
    else if (g < G_UW1) { src = uw1; dst = uw1b; off = (g - G_W1) * 8; }
    else                { src = uw2; dst = uw2b; off = (g - G_UW1) * 8; }
    float4 a = *(const float4*)(src + off);
    float4 b = *(const float4*)(src + off + 4);
    bf16x8 o;
    o[0] = (__bf16)a.x; o[1] = (__bf16)a.y; o[2] = (__bf16)a.z; o[3] = (__bf16)a.w;
    o[4] = (__bf16)b.x; o[5] = (__bf16)b.y; o[6] = (__bf16)b.z; o[7] = (__bf16)b.w;
    *(bf16x8*)(dst + off) = o;
}

// ---- scan phase 1: per-512-node partial sums
__global__ __launch_bounds__(256) void k_scan1(const int* __restrict__ deg,
                                               int* __restrict__ psum) {
    __shared__ int red[256];
    int b = blockIdx.x, t = threadIdx.x;
    int i = b * 512 + t * 2;
    int s = 0;
    if (i < N_NODES_C) s += deg[i];
    if (i + 1 < N_NODES_C) s += deg[i + 1];
    red[t] = s;
    __syncthreads();
#pragma unroll
    for (int off = 128; off > 0; off >>= 1) {
        if (t < off) red[t] += red[t + off];
        __syncthreads();
    }
    if (t == 0) psum[b] = red[0];
}

// ---- scan phase 2+3 fused: each block redundantly reduces psum prefix (wave 0)
__global__ __launch_bounds__(256) void k_scan3(const int* __restrict__ deg,
                                               const int* __restrict__ psum,
                                               int* __restrict__ offsets,
                                               int* __restrict__ cursor) {
    __shared__ int sc[256];
    __shared__ int bo[2];
    int b = blockIdx.x, t = threadIdx.x;
    if (t < 64) {
        int v1 = (t < SCAN_B) ? psum[t] : 0;
        int v2 = (t + 64 < SCAN_B) ? psum[t + 64] : 0;
        int c   = ((t < b) ? v1 : 0) + ((t + 64 < b) ? v2 : 0);
        int tot = v1 + v2;
#pragma unroll
        for (int off = 32; off > 0; off >>= 1) {
            c   += __shfl_xor(c, off, 64);
            tot += __shfl_xor(tot, off, 64);
        }
        if (t == 0) { bo[0] = c; bo[1] = tot; }
    }
    int i = b * 512 + t * 2;
    int d0 = (i < N_NODES_C) ? deg[i] : 0;
    int d1 = (i + 1 < N_NODES_C) ? deg[i + 1] : 0;
    int s = d0 + d1;
    sc[t] = s;
    __syncthreads();
#pragma unroll
    for (int off = 1; off < 256; off <<= 1) {
        int val = sc[t];
        int add = (t >= off) ? sc[t - off] : 0;
        __syncthreads();
        sc[t] = val + add;
        __syncthreads();
    }
    int excl = bo[0] + sc[t] - s;
    if (i < N_NODES_C)     { offsets[i]     = excl;      cursor[i]     = excl; }
    if (i + 1 < N_NODES_C) { offsets[i + 1] = excl + d0; cursor[i + 1] = excl + d0; }
    if (b == 0 && t == 0)  offsets[N_NODES_C] = bo[1];
}

// ---- CSR fill: (src,dst,e) records
__global__ __launch_bounds__(256) void k_fill(const int* __restrict__ ei,
                                              int* __restrict__ cursor,
                                              int4* __restrict__ csr) {
    int e = blockIdx.x * blockDim.x + threadIdx.x;
    if (e < E_C) {
        int src  = ei[e];
        int dst  = ei[E_C + e];
        int slot = atomicAdd(&cursor[dst], 1);
        csr[slot] = make_int4(src, dst, e, 0);
    }
}

// ---- A-fragment gather (ef indexed by original edge id e)
__device__ __forceinline__ void load_afrags(
    int src, int dst, int e, int quad,
    const __bf16* __restrict__ xb, const __bf16* __restrict__ xsb,
    const __bf16* __restrict__ efb,
    bf16x8 a[6])
{
    const __bf16* px = xb + (long)src * 64 + quad * 8;
    const __bf16* pd = xb + (long)dst * 64 + quad * 8;
    a[0] = *(const bf16x8*)(px);
    a[1] = *(const bf16x8*)(px + 32);
    a[2] = *(const bf16x8*)(pd);
    a[3] = *(const bf16x8*)(pd + 32);
    if (quad < 2) {
        a[4] = *(const bf16x8*)(xsb + (long)src * 16 + quad * 8);
        a[5] = *(const bf16x8*)(efb + (long)e * 16 + quad * 8);
    } else {
        a[4] = *(const bf16x8*)(xsb + (long)dst * 16 + (quad - 2) * 8);
        a[5] = bzero8();
    }
}

// ---- edge attention MLP via bf16 MFMA, CSR-ordered, 2-tile ILP.
// W1 fragments live in LDS (53KB, stride 184 = 16B-aligned, 2-way bank alias
// only = free). This frees ~216 regs vs the in-register B version so the
// allocator can land <=256 total and fit 2 waves/SIMD (the round-7 kernel was
// pinned at 1 wave/SIMD by the unified VGPR+AGPR file, which capped in-flight
// gathers at the bandwidth-delay product). No min-waves bound (round-5 spill).
__global__ __launch_bounds__(256) void k_scores_mfma(
    const __bf16* __restrict__ xb, const __bf16* __restrict__ xsb,
    const __bf16* __restrict__ efb, const __bf16* __restrict__ w1b,
    const int4* __restrict__ csr,
    const float* __restrict__ b1, const float* __restrict__ w2,
    const float* __restrict__ b2, float* __restrict__ raw)
{
    __shared__ __bf16 w1s[144 * 184];   // 52,992 B
    int tid  = threadIdx.x;
    int lane = tid & 63;

    // cooperative W1 load: 144 rows x 22 chunks of bf16x8
    for (int c = tid; c < 144 * 22; c += 256) {
        int n = c / 22, kk = (c % 22) * 8;
        *(bf16x8*)&w1s[n * 184 + kk] = *(const bf16x8*)(w1b + (long)n * ATT_IN_C + kk);
    }
    for (int n = tid; n < 144; n += 256)
        *(bf16x8*)&w1s[n * 184 + 176] = bzero8();   // zero the pad (NaN safety)
    __syncthreads();

    int w = blockIdx.x * 4 + (tid >> 6);      // global wave 0..1023
    const int NP = E_C / 32;                  // 25000 edge-pairs
    int per = (NP + 1023) / 1024;             // 25
    long j0 = (long)w * per;
    long j1 = j0 + per; if (j1 > NP) j1 = NP;
    if (j0 >= j1) return;

    int mrow = lane & 15;
    int quad = lane >> 4;
    const __bf16* wls = &w1s[mrow * 184 + quad * 8];

    float b1v[9], w2v[9];
#pragma unroll
    for (int nt = 0; nt < 9; ++nt) {
        int n = nt * 16 + mrow;
        b1v[nt] = b1[n];
        w2v[nt] = w2[n];
    }
    float b2v = b2[0];

    bf16x8 curA[6], curB[6], nxtA[6], nxtB[6];
    int4 cA = make_int4(0, 0, 0, 0), cB = cA;
    {
        int4 e0 = csr[j0 * 32 + mrow];
        int4 e1 = csr[j0 * 32 + 16 + mrow];
        load_afrags(e0.x, e0.y, e0.z, quad, xb, xsb, efb, curA);
        load_afrags(e1.x, e1.y, e1.z, quad, xb, xsb, efb, curB);
        if (j0 + 1 < j1) {
            int4 f0 = csr[(j0 + 1) * 32 + mrow];
            int4 f1 = csr[(j0 + 1) * 32 + 16 + mrow];
            load_afrags(f0.x, f0.y, f0.z, quad, xb, xsb, efb, nxtA);
            load_afrags(f1.x, f1.y, f1.z, quad, xb, xsb, efb, nxtB);
        }
    }

    for (long j = j0; j < j1; ++j) {
        if (j + 2 < j1) {
            cA = csr[(j + 2) * 32 + mrow];
            cB = csr[(j + 2) * 32 + 16 + mrow];
        }

        f32x4 accA[9], accB[9];
#pragma unroll
        for (int nt = 0; nt < 9; ++nt) {
            accA[nt] = (f32x4){0.f, 0.f, 0.f, 0.f};
            accB[nt] = (f32x4){0.f, 0.f, 0.f, 0.f};
        }

#pragma unroll
        for (int ks = 0; ks < 6; ++ks) {
#pragma unroll
            for (int nt = 0; nt < 9; ++nt) {
                bf16x8 bf = *(const bf16x8*)(wls + nt * (16 * 184) + ks * 32);
                accA[nt] = __builtin_amdgcn_mfma_f32_16x16x32_bf16(
                    curA[ks], bf, accA[nt], 0, 0, 0);
                accB[nt] = __builtin_amdgcn_mfma_f32_16x16x32_bf16(
                    curB[ks], bf, accB[nt], 0, 0, 0);
            }
        }

        float pA0 = 0.f, pA1 = 0.f, pA2 = 0.f, pA3 = 0.f;
        float pB0 = 0.f, pB1 = 0.f, pB2 = 0.f, pB3 = 0.f;
#pragma unroll
        for (int nt = 0; nt < 9; ++nt) {
            pA0 += w2v[nt] * fmaxf(accA[nt][0] + b1v[nt], 0.f);
            pA1 += w2v[nt] * fmaxf(accA[nt][1] + b1v[nt], 0.f);
            pA2 += w2v[nt] * fmaxf(accA[nt][2] + b1v[nt], 0.f);
            pA3 += w2v[nt] * fmaxf(accA[nt][3] + b1v[nt], 0.f);
            pB0 += w2v[nt] * fmaxf(accB[nt][0] + b1v[nt], 0.f);
            pB1 += w2v[nt] * fmaxf(accB[nt][1] + b1v[nt], 0.f);
            pB2 += w2v[nt] * fmaxf(accB[nt][2] + b1v[nt], 0.f);
            pB3 += w2v[nt] * fmaxf(accB[nt][3] + b1v[nt], 0.f);
        }
#pragma unroll
        for (int off = 1; off < 16; off <<= 1) {
            pA0 += __shfl_xor(pA0, off, 64);
            pA1 += __shfl_xor(pA1, off, 64);
            pA2 += __shfl_xor(pA2, off, 64);
            pA3 += __shfl_xor(pA3, off, 64);
            pB0 += __shfl_xor(pB0, off, 64);
            pB1 += __shfl_xor(pB1, off, 64);
            pB2 += __shfl_xor(pB2, off, 64);
            pB3 += __shfl_xor(pB3, off, 64);
        }
        if (mrow < 4) {
            float vA = (mrow == 0) ? pA0 : (mrow == 1) ? pA1 : (mrow == 2) ? pA2 : pA3;
            float vB = (mrow == 0) ? pB0 : (mrow == 1) ? pB1 : (mrow == 2) ? pB2 : pB3;
            vA += b2v; vB += b2v;
            vA = (vA >= 0.f) ? vA : 0.01f * vA;
            vB = (vB >= 0.f) ? vB : 0.01f * vB;
            raw[(j * 2) * 16 + quad * 4 + mrow]     = vA;
            raw[(j * 2 + 1) * 16 + quad * 4 + mrow] = vB;
        }

#pragma unroll
        for (int i = 0; i < 6; ++i) { curA[i] = nxtA[i]; curB[i] = nxtB[i]; }
        if (j + 2 < j1) {
            load_afrags(cA.x, cA.y, cA.z, quad, xb, xsb, efb, nxtA);
            load_afrags(cB.x, cB.y, cB.z, quad, xb, xsb, efb, nxtB);
        }
    }
}

// ---- per-node segment softmax + weighted gather -> bf16 agg (4-deep MLP)
__global__ __launch_bounds__(256) void k_agg(
    const __bf16* __restrict__ xb, const int* __restrict__ offsets,
    const int4* __restrict__ csr,
    const float* __restrict__ raw, __bf16* __restrict__ aggb)
{
    int tid = threadIdx.x;
    int wave = tid >> 6, lane = tid & 63;
    int v = blockIdx.x * 4 + wave;
    if (v >= N_NODES_C) return;
    int s0 = offsets[v], s1 = offsets[v + 1];

    float m = -INFINITY;
    for (int p = s0 + lane; p < s1; p += 64) m = fmaxf(m, raw[p]);
#pragma unroll
    for (int off = 32; off > 0; off >>= 1) m = fmaxf(m, __shfl_xor(m, off, 64));

    float acc = 0.f, sum = 0.f;
    int p = s0;
    for (; p + 4 <= s1; p += 4) {
        int4 c0 = csr[p], c1 = csr[p + 1], c2 = csr[p + 2], c3 = csr[p + 3];
        float r0 = raw[p], r1 = raw[p + 1], r2 = raw[p + 2], r3 = raw[p + 3];
        float v0 = (float)xb[(long)c0.x * 64 + lane];
        float v1 = (float)xb[(long)c1.x * 64 + lane];
        float v2 = (float)xb[(long)c2.x * 64 + lane];
        float v3 = (float)xb[(long)c3.x * 64 + lane];
        float w0 = expf(r0 - m), w1 = expf(r1 - m);
        float w2 = expf(r2 - m), w3 = expf(r3 - m);
        sum += (w0 + w1) + (w2 + w3);
        acc += w0 * v0 + w1 * v1 + w2 * v2 + w3 * v3;
    }
    for (; p < s1; ++p) {
        int src = csr[p].x;
        float w = expf(raw[p] - m);
        sum += w;
        acc += w * (float)xb[(long)src * 64 + lane];
    }
    aggb[(long)v * 64 + lane] = (__bf16)(acc / (sum + 1e-9f));
}

// ---- node update MLP via bf16 MFMA: one wave = 16 nodes
__global__ __launch_bounds__(256) void k_upd_mfma(
    const __bf16* __restrict__ xb, const __bf16* __restrict__ aggb,
    const __bf16* __restrict__ w1b, const float* __restrict__ b1,
    const __bf16* __restrict__ w2b, const float* __restrict__ b2,
    float* __restrict__ out)
{
    __shared__ __bf16 ubuf[4][16 * 136];
    int tid = threadIdx.x, wid = tid >> 6, lane = tid & 63;
    int tile = blockIdx.x * 4 + wid;
    if (tile >= UPD_TILES) return;
    int mrow = lane & 15, quad = lane >> 4;

    long node = (long)tile * 16 + mrow;
    bf16x8 a1[4];
    a1[0] = *(const bf16x8*)(xb + node * 64 + quad * 8);
    a1[1] = *(const bf16x8*)(xb + node * 64 + 32 + quad * 8);
    a1[2] = *(const bf16x8*)(aggb + node * 64 + quad * 8);
    a1[3] = *(const bf16x8*)(aggb + node * 64 + 32 + quad * 8);

    bf16x8 b1f[4][8];
#pragma unroll
    for (int ks = 0; ks < 4; ++ks)
#pragma unroll
        for (int nt = 0; nt < 8; ++nt)
            b1f[ks][nt] = *(const bf16x8*)(w1b + (long)(nt * 16 + mrow) * 128 + ks * 32 + quad * 8);

    f32x4 acc1[8];
#pragma unroll
    for (int nt = 0; nt < 8; ++nt) acc1[nt] = (f32x4){0.f, 0.f, 0.f, 0.f};
#pragma unroll
    for (int ks = 0; ks < 4; ++ks)
#pragma unroll
        for (int nt = 0; nt < 8; ++nt)
            acc1[nt] = __builtin_amdgcn_mfma_f32_16x16x32_bf16(a1[ks], b1f[ks][nt], acc1[nt], 0, 0, 0);

    __bf16* ub = ubuf[wid];
#pragma unroll
    for (int nt = 0; nt < 8; ++nt) {
        float bb = b1[nt * 16 + mrow];
#pragma unroll
        for (int r = 0; r < 4; ++r) {
            float h = fmaxf(acc1[nt][r] + bb, 0.f);
            ub[(quad * 4 + r) * 136 + nt * 16 + mrow] = (__bf16)h;
        }
    }

    bf16x8 a2[4];
#pragma unroll
    for (int ks = 0; ks < 4; ++ks)
        a2[ks] = *(bf16x8*)&ub[mrow * 136 + ks * 32 + quad * 8];

    bf16x8 b2f[4][4];
#pragma unroll
    for (int ks = 0; ks < 4; ++ks)
#pragma unroll
        for (int nt = 0; nt < 4; ++nt)
            b2f[ks][nt] = *(const bf16x8*)(w2b + (long)(nt * 16 + mrow) * 128 + ks * 32 + quad * 8);

    f32x4 acc2[4];
#pragma unroll
    for (int nt = 0; nt < 4; ++nt) acc2[nt] = (f32x4){0.f, 0.f, 0.f, 0.f};
#pragma unroll
    for (int ks = 0; ks < 4; ++ks)
#pragma unroll
        for (int nt = 0; nt < 4; ++nt)
            acc2[nt] = __builtin_amdgcn_mfma_f32_16x16x32_bf16(a2[ks], b2f[ks][nt], acc2[nt], 0, 0, 0);

#pragma unroll
    for (int nt = 0; nt < 4; ++nt) {
        float bb = b2[nt * 16 + mrow];
#pragma unroll
        for (int r = 0; r < 4; ++r) {
            long nodeo = (long)tile * 16 + quad * 4 + r;
            out[nodeo * 64 + nt * 16 + mrow] = fmaxf(acc2[nt][r] + bb, 0.f);
        }
    }
}

extern "C" void kernel_launch(void* const* d_in, const int* in_sizes, int n_in,
                              void* d_out, int out_size, void* d_ws, size_t ws_size,
                              hipStream_t stream) {
    const float* x    = (const float*)d_in[0];
    const float* xs   = (const float*)d_in[1];
    const int*   ei   = (const int*)d_in[2];
    const float* ef   = (const float*)d_in[3];
    const float* aw1  = (const float*)d_in[4];
    const float* ab1  = (const float*)d_in[5];
    const float* aw2  = (const float*)d_in[6];
    const float* ab2  = (const float*)d_in[7];
    const float* uw1  = (const float*)d_in[8];
    const float* ub1  = (const float*)d_in[9];
    const float* uw2  = (const float*)d_in[10];
    const float* ub2  = (const float*)d_in[11];
    float* out = (float*)d_out;

    char* ws = (char*)d_ws;
    float*  raw     = (float*)(ws + O_RAW);
    int*    deg     = (int*)(ws + O_DEG);
    int*    offsets = (int*)(ws + O_OFF);
    int*    cursor  = (int*)(ws + O_CUR);
    int4*   csr     = (int4*)(ws + O_CSR);
    __bf16* efb     = (__bf16*)(ws + O_EFB);
    __bf16* xb      = (__bf16*)(ws + O_XB);
    __bf16* xsb     = (__bf16*)(ws + O_XSB);
    __bf16* w1b     = (__bf16*)(ws + O_W1B);
    __bf16* uw1b    = (__bf16*)(ws + O_UW1B);
    __bf16* uw2b    = (__bf16*)(ws + O_UW2B);
    __bf16* aggb    = (__bf16*)(ws + O_AGGB);
    int*    psum    = (int*)(ws + O_PSUM);

    hipMemsetAsync(deg, 0, N_NODES_C * sizeof(int), stream);
    hipLaunchKernelGGL(k_prep,     dim3(DEG_B + CVT_B),           dim3(256), 0, stream,
                       ei, x, xs, ef, aw1, uw1, uw2, deg, xb, xsb, efb, w1b, uw1b, uw2b);
    hipLaunchKernelGGL(k_scan1,    dim3(SCAN_B),                  dim3(256), 0, stream, deg, psum);
    hipLaunchKernelGGL(k_scan3,    dim3(SCAN_B),                  dim3(256), 0, stream,
                       deg, psum, offsets, cursor);
    hipLaunchKernelGGL(k_fill,     dim3((E_C + 255) / 256),       dim3(256), 0, stream,
                       ei, cursor, csr);
    hipLaunchKernelGGL(k_scores_mfma, dim3(256),                  dim3(256), 0, stream,
                       xb, xsb, efb, w1b, csr, ab1, aw2, ab2, raw);
    hipLaunchKernelGGL(k_agg,      dim3((N_NODES_C + 3) / 4),     dim3(256), 0, stream,
                       xb, offsets, csr, raw, aggb);
    hipLaunchKernelGGL(k_upd_mfma, dim3((UPD_TILES + 3) / 4),     dim3(256), 0, stream,
                       xb, aggb, uw1b, ub1, uw2b, ub2, out);
}